// Round 12
// baseline (264.616 us; speedup 1.0000x reference)
//
#include <hip/hip_runtime.h>
#include <math.h>

// MEASUREMENT ROUND (x16 duplicated grid) + A-fragment hoisting.
// Fused ConvTranspose3d(16->32, K=3, s=2, p=1) + MaxPool3d(6) + channel-sum.
// Block = (n,pd,ph) row of 10 pooled cells, 256 thr / 4 waves; each wave owns
// whole cells (3/3/2/2). Per cell: the 27 taps touch only 8 DISTINCT
// A-fragments (oz,oy,ox in {0,1}^3) -> load 8 short8 once, run all 8 parity
// classes against them (27 MFMAs), running max md across classes, one rowmax,
// in-wave bias + channel-sum, direct store (no red LDS, one barrier total).
// Grid = 16 x 800; duplicate blocks recompute identical values (benign,
// deterministic) so fused_mfma ranks above the ~43us harness fills and
// exposes its rocprof counters. Marginal warm rate = (dur-80)/15.

namespace {

typedef __attribute__((ext_vector_type(8))) short short8;
typedef __attribute__((ext_vector_type(16))) float f32x16;

// class-ordered tap -> kd*9+kh*3+kw; class c=PA*4+PB*2+PC, within-class
// (a,b,c) with a==0 -> k=0, a==1 -> k=2 on P=1 axes. bases {0,1,3,5,9,11,15,19}
__constant__ int JK[27] = {13, 12, 14, 10, 16, 9,  11, 15, 17, 4,  22, 3,  5, 21,
                           23, 1,  7,  19, 25, 0,  2,  6,  8,  18, 20, 24, 26};

__device__ __forceinline__ uint f2bf(float f) {
  uint u = __float_as_uint(f);
  return (u + 0x7FFFu + ((u >> 16) & 1u)) >> 16;  // RNE bf16 bits
}

__global__ void prep_w(const float* __restrict__ w, ushort* __restrict__ w2) {
  const int o = blockIdx.x * 256 + threadIdx.x;  // 27*2*32*8 = 13824
  const int t2 = o >> 9;         // class-ordered tap
  const int cih = (o >> 8) & 1;  // k-half
  const int co = (o >> 3) & 31;
  const int ci = cih * 8 + (o & 7);
  w2[o] = (ushort)f2bf(w[(ci * 32 + co) * 27 + JK[t2]]);
}

__device__ __forceinline__ f32x16 zero16() {
  f32x16 d;
#pragma unroll
  for (int i = 0; i < 16; ++i) d[i] = 0.f;
  return d;
}

template <int CC, int BASE>
__device__ __forceinline__ void class_accum(f32x16& d,
                                            const ushort* __restrict__ w2l,
                                            const short8 (&av)[8]) {
  constexpr int PA = (CC >> 2) & 1, PB = (CC >> 1) & 1, PC = CC & 1;
  constexpr int NTZ = PA ? 2 : 1, NTY = PB ? 2 : 1, NTX = PC ? 2 : 1;
#pragma unroll
  for (int a = 0; a < NTZ; ++a) {
    const int oz = PA ? (a ? 0 : 1) : 0;
#pragma unroll
    for (int b = 0; b < NTY; ++b) {
      const int oy = PB ? (b ? 0 : 1) : 0;
#pragma unroll
      for (int c = 0; c < NTX; ++c) {
        const int ox = PC ? (c ? 0 : 1) : 0;
        const short8 bv = *reinterpret_cast<const short8*>(
            w2l + (BASE + (a * NTY + b) * NTX + c) * 512);
        d = __builtin_amdgcn_mfma_f32_32x32x16_bf16(av[oz * 4 + oy * 2 + ox],
                                                    bv, d, 0, 0, 0);
      }
    }
  }
}

__device__ __forceinline__ float rowmax(const f32x16& d, int hi) {
  // rows: (reg&3)+8*(reg>>2)+4*hi; valid rows < 27 -> regs 0..11 both halves,
  // regs 12..14 only hi==0, reg 15 never.
  float ma = d[0];
#pragma unroll
  for (int i = 1; i < 12; ++i) ma = fmaxf(ma, d[i]);
  const float mb = fmaxf(fmaxf(d[12], d[13]), d[14]);
  return hi ? ma : fmaxf(ma, mb);
}

__device__ __forceinline__ void do_cell(int pw, int l, int hi, int co, int kp,
                                        const uint lin[2][2],
                                        const int zy4[2][2],
                                        const ushort* __restrict__ w2l,
                                        const ushort* __restrict__ xs,
                                        const float* __restrict__ bias,
                                        float* __restrict__ out, int lb) {
  // 8 distinct A-fragments for this cell
  short8 av[8];
  const char* xb = reinterpret_cast<const char*>(xs);
  const int cellk = 3 * pw + kp;
#pragma unroll
  for (int oz = 0; oz < 2; ++oz)
#pragma unroll
    for (int oy = 0; oy < 2; ++oy)
#pragma unroll
      for (int ox = 0; ox < 2; ++ox) {
        const int xcol = cellk + ox;
        const uint addr = (lin[oz][oy] + (uint)(xcol << 5)) ^
                          ((uint)(((zy4[oz][oy] ^ (xcol >> 2)) & 7)) << 4);
        av[oz * 4 + oy * 2 + ox] = *reinterpret_cast<const short8*>(xb + addr);
      }

  f32x16 d = zero16();
  class_accum<7, 19>(d, w2l, av);
  f32x16 md = d;
#define MDSTEP(CC, BASE)            \
  d = zero16();                     \
  class_accum<CC, BASE>(d, w2l, av);\
  _Pragma("unroll") for (int i = 0; i < 16; ++i) md[i] = fmaxf(md[i], d[i]);
  MDSTEP(6, 15)
  MDSTEP(5, 11)
  MDSTEP(4, 9)
  MDSTEP(3, 5)
  MDSTEP(2, 3)
  MDSTEP(1, 1)
  MDSTEP(0, 0)
#undef MDSTEP

  float m = rowmax(md, hi);
  m = fmaxf(m, __shfl_xor(m, 32));  // combine row-halves (both halves equal)
  // + bias, channel-sum within the wave, direct store
  float v = m + bias[co];
#pragma unroll
  for (int off = 16; off >= 1; off >>= 1) v += __shfl_xor(v, off);
  if (l == 0) out[lb * 10 + pw] = v;
}

__global__ __launch_bounds__(256, 3) void fused_mfma(
    const float* __restrict__ x, const ushort* __restrict__ w2,
    const float* __restrict__ bias, float* __restrict__ out) {
  __shared__ __align__(16) ushort xs[8192];  // 16 KB swizzled [z][y][xcol][ci]

  const int t = threadIdx.x;
  const int wv = t >> 6;
  const int l = t & 63;
  const int hi = l >> 5;
  const int co = l & 31;

  const int bd = blockIdx.x % 800;  // x16 duplicated grid
  // chunked bijective XCD swizzle (800 = 8 * 100)
  const int lb = (bd & 7) * 100 + (bd >> 3);
  const int n = lb / 100, pd = (lb / 10) % 10, ph = lb % 10;

  // ---- stage: 16ci x 4z x 4y x 32xcol floats, coalesced float4 rows ----
  {
    const float* xg =
        x + (size_t)n * 524288 + (size_t)(3 * pd) * 1024 + (3 * ph) * 32;
#pragma unroll
    for (int j = 0; j < 8; ++j) {
      const int fi = j * 256 + t;  // float4 index, 2048 total
      const int r = fi >> 3;       // row 0..255 = (ci,z,y)
      const int xq = fi & 7;
      const int ci = r >> 4, z = (r >> 2) & 3, y = r & 3;
      const float4 v = *reinterpret_cast<const float4*>(
          xg + (size_t)ci * 32768 + z * 1024 + y * 32 + xq * 4);
      const uint base = (uint)((z << 12) + (y << 10) + ((ci >> 3) << 4) +
                               ((ci & 7) << 1));
      const uint swz = (uint)((((z * 4 + y) ^ xq) & 7)) << 4;
      char* xb = reinterpret_cast<char*>(xs);
      *(ushort*)(xb + ((base + ((uint)(4 * xq + 0) << 5)) ^ swz)) =
          (ushort)f2bf(v.x);
      *(ushort*)(xb + ((base + ((uint)(4 * xq + 1) << 5)) ^ swz)) =
          (ushort)f2bf(v.y);
      *(ushort*)(xb + ((base + ((uint)(4 * xq + 2) << 5)) ^ swz)) =
          (ushort)f2bf(v.z);
      *(ushort*)(xb + ((base + ((uint)(4 * xq + 3) << 5)) ^ swz)) =
          (ushort)f2bf(v.w);
    }
  }
  __syncthreads();

  // ---- per-lane A geometry: position p = lane&31 (rows 27..31 dup 26) ----
  const int p = co > 26 ? 26 : co;
  const int ip = p / 9, jp = (p / 3) % 3, kp = p % 3;
  uint lin[2][2];
  int zy4[2][2];
#pragma unroll
  for (int oz = 0; oz < 2; ++oz)
#pragma unroll
    for (int oy = 0; oy < 2; ++oy) {
      const int z = ip + oz, y = jp + oy;
      lin[oz][oy] = (uint)((z << 12) + (y << 10) + (hi << 4));
      zy4[oz][oy] = z * 4 + y;
    }

  const ushort* w2l = w2 + hi * 256 + co * 8;

  // waves 0,1: cells {wv, wv+4, wv+8}; waves 2,3: cells {wv, wv+4}
  for (int c = wv; c < 10; c += 4)
    do_cell(c, l, hi, co, kp, lin, zy4, w2l, xs, bias, out, lb);
}

}  // namespace

extern "C" void kernel_launch(void* const* d_in, const int* in_sizes, int n_in,
                              void* d_out, int out_size, void* d_ws,
                              size_t ws_size, hipStream_t stream) {
  const float* x = (const float*)d_in[0];
  const float* w = (const float*)d_in[1];
  const float* b = (const float*)d_in[2];
  float* out = (float*)d_out;
  ushort* w2 = (ushort*)d_ws;  // 13824 ushort = 27648 B
  prep_w<<<54, 256, 0, stream>>>(w, w2);
  fused_mfma<<<800 * 16, 256, 0, stream>>>(x, w2, b, out);  // x16 measurement
}